// Round 1
// baseline (23197.865 us; speedup 1.0000x reference)
//
#include <hip/hip_runtime.h>

typedef short short8 __attribute__((ext_vector_type(8)));
typedef float f32x4 __attribute__((ext_vector_type(4)));

// one 128x68 f32 reduction tile + 4x128 fc-reduce
#define SMEM_BYTES (128*68*4 + 4*128*4)

__device__ __forceinline__ unsigned short f2bf(float x) {
    unsigned int u = __float_as_uint(x);
    u += 0x7FFFu + ((u >> 16) & 1u);   // round-to-nearest-even
    return (unsigned short)(u >> 16);
}

__device__ __forceinline__ float sigmoidf_(float x) {
    return 1.0f / (1.0f + __expf(-x));
}

__device__ __forceinline__ float tanhf_(float x) {
    float ax = fabsf(x);
    float e = __expf(2.0f * ax);
    float t = 1.0f - 2.0f / (e + 1.0f);
    return copysignf(t, x);
}

// ---------------- packed layouts ----------------
// hP  [rg 16][kc 32][lane 64][j 8]  (lane = q*16+m holds h[rg*16+m][kc*32+q*8+j])
// WP  [ug 64][kc K/32][gate 4][lane 64][j 8]
// Every K-loop load is base + lane*16B -> one contiguous 1 KB per instruction.

// One LSTM step tile: 128 batch rows x 16 units (x4 gates), 512 threads.
// 8 waves = (mh: row-half) x (kq: K-quarter). Inner pipeline identical to the
// 64-row version (4x4 MFMA blocking, 4-stage register pipeline, ~224 VGPR ->
// amdgpu_waves_per_eu(2,2)). Bg=2 instead of Bg=4 halves weight re-reads:
// per-step L2 traffic 192MB -> 144MB. K-split reduced through ONE 128x68 LDS
// tile: kq==0 writes, kq!=0 ds_add_f32 (single tile keeps LDS under 64KB).
// Prefetch overruns up to 3 chunks past the slice end -> guard memory required.
//
// xdone/xneed: optional device-scope spin (epilogue only) so a fused launch can
// consume y produced by sibling blocks of the SAME launch (decoder pipelining).
// ydone: bumped once per block after this block's fc atomics are drained.
template<int K>
__device__ __forceinline__ void lstm_tile(
    int idx,
    const unsigned short* __restrict__ A1,   // hP, first K-half
    const unsigned short* __restrict__ A2,   // hP, second K-half (K==2048) or null
    const unsigned short* __restrict__ W,    // WP packed
    const float* __restrict__ bias,          // [4096]
    const float* __restrict__ xvec, int xstride,
    const float* __restrict__ Wx,            // [4096] or null
    float* __restrict__ c,                   // [256,1024] fp32 in-place
    unsigned short* __restrict__ hout,       // hP packed out
    const float* __restrict__ fcW,
    const float* __restrict__ fcb,
    float* __restrict__ yout,
    const int* xdone, int xneed, int* ydone)
{
    extern __shared__ float smem[];
    float* T   = smem;                 // 128 x 68
    float* red = smem + 128 * 68;      // 4 x 128

    constexpr int KS = K / 4;
    constexpr int NC = KS / 32;        // chunks per wave (8 or 16)
    constexpr int KC = K / 32;
    const int tid  = threadIdx.x;
    const int lane = tid & 63;
    const int wave = tid >> 6;
    const int kq   = wave & 3;         // K-quarter
    const int mh   = wave >> 2;        // row-half (0/1)
    const int g  = idx >> 6;           // batch group (128 rows)
    const int ug = idx & 63;           // unit group (16 units)
    const int mb = g * 128;
    const int ub = ug * 16;

    const unsigned short* Af = (K == 1024) ? A1 : (kq < 2 ? A1 : A2);
    const int kcA0 = (kq * NC) & 31;
    const int kcW0 = kq * NC;
    const unsigned short* ap = Af + ((size_t)((g * 8 + mh * 4) * 32 + kcA0)) * 512 + lane * 8;
    const unsigned short* bp = W + ((size_t)(ug * KC + kcW0) * 4) * 512 + lane * 8;

    f32x4 acc[4][4];
#pragma unroll
    for (int i = 0; i < 4; ++i)
#pragma unroll
        for (int j = 0; j < 4; ++j) acc[i][j] = (f32x4){0.f, 0.f, 0.f, 0.f};

    short8 aS[4][4], bS[4][4];
    auto LD = [&](int s, int cc) {
#pragma unroll
        for (int mi = 0; mi < 4; ++mi)
            aS[s][mi] = *(const short8*)(ap + mi * 16384 + cc * 512);
#pragma unroll
        for (int gt = 0; gt < 4; ++gt)
            bS[s][gt] = *(const short8*)(bp + (cc * 4 + gt) * 512);
    };
    auto MM = [&](int s) {
#pragma unroll
        for (int mi = 0; mi < 4; ++mi)
#pragma unroll
            for (int gt = 0; gt < 4; ++gt)
                acc[mi][gt] = __builtin_amdgcn_mfma_f32_16x16x32_bf16(
                    aS[s][mi], bS[s][gt], acc[mi][gt], 0, 0, 0);
    };

    LD(0, 0); LD(1, 1); LD(2, 2); LD(3, 3);
#pragma unroll
    for (int cc = 0; cc < NC; cc += 4) {
        MM(0); LD(0, cc + 4);    // tail iters overrun into guard memory
        MM(1); LD(1, cc + 5);
        MM(2); LD(2, cc + 6);
        MM(3); LD(3, cc + 7);
    }

    // ---- K-split reduction through LDS (single tile, ds_add for kq!=0) ----
    const int q = lane >> 4;
    const int m = lane & 15;
    if (kq == 0) {
#pragma unroll
        for (int mi = 0; mi < 4; ++mi)
#pragma unroll
            for (int gt = 0; gt < 4; ++gt)
#pragma unroll
                for (int r = 0; r < 4; ++r)
                    T[(mh * 64 + mi * 16 + q * 4 + r) * 68 + gt * 16 + m] = acc[mi][gt][r];
    }
    __syncthreads();
    if (kq != 0) {
#pragma unroll
        for (int mi = 0; mi < 4; ++mi)
#pragma unroll
            for (int gt = 0; gt < 4; ++gt)
#pragma unroll
                for (int r = 0; r < 4; ++r)
                    atomicAdd(&T[(mh * 64 + mi * 16 + q * 4 + r) * 68 + gt * 16 + m],
                              acc[mi][gt][r]);
    }
    __syncthreads();

    // ---- epilogue: thread owns (row = tid>>2, units u0..u0+3) ----
    const int lrow = tid >> 2;
    const int uq   = tid & 3;
    const int br   = mb + lrow;
    const int u0   = ub + uq * 4;
    const int toff = lrow * 68 + uq * 4;

    float4 GI = *(const float4*)(T + toff + 0);
    float4 GF = *(const float4*)(T + toff + 16);
    float4 GG = *(const float4*)(T + toff + 32);
    float4 GO = *(const float4*)(T + toff + 48);
    float4 bI = *(const float4*)(bias + u0);
    float4 bF = *(const float4*)(bias + 1024 + u0);
    float4 bG = *(const float4*)(bias + 2048 + u0);
    float4 bO = *(const float4*)(bias + 3072 + u0);
    float4 wI = {0,0,0,0}, wF = {0,0,0,0}, wG = {0,0,0,0}, wO = {0,0,0,0};
    float xv = 0.f;
    if (xvec) {
        if (xdone) {
            // y[s-1] is produced by sibling blocks of this launch; wait for all
            // producer blocks, then read coherently (L2/coherence point).
            if (tid == 0) {
                while (__hip_atomic_load(xdone, __ATOMIC_ACQUIRE,
                                         __HIP_MEMORY_SCOPE_AGENT) < xneed)
                    __builtin_amdgcn_s_sleep(4);
            }
            __syncthreads();
            xv = __hip_atomic_load(xvec + (size_t)br * xstride,
                                   __ATOMIC_RELAXED, __HIP_MEMORY_SCOPE_AGENT);
        } else {
            xv = xvec[(size_t)br * xstride];
        }
        wI = *(const float4*)(Wx + u0);
        wF = *(const float4*)(Wx + 1024 + u0);
        wG = *(const float4*)(Wx + 2048 + u0);
        wO = *(const float4*)(Wx + 3072 + u0);
    }
    float4 cc = *(const float4*)(c + (size_t)br * 1024 + u0);

    auto cellc = [&](float gi, float gf, float gg, float go, float cold, float& hO) -> float {
        float i = sigmoidf_(gi);
        float f = sigmoidf_(gf);
        float o = sigmoidf_(go);
        float cn = f * cold + i * tanhf_(gg);
        hO = o * tanhf_(cn);
        return cn;
    };
    float h0v, h1v, h2v, h3v;
    float4 cn;
    cn.x = cellc(GI.x + bI.x + xv * wI.x, GF.x + bF.x + xv * wF.x,
                 GG.x + bG.x + xv * wG.x, GO.x + bO.x + xv * wO.x, cc.x, h0v);
    cn.y = cellc(GI.y + bI.y + xv * wI.y, GF.y + bF.y + xv * wF.y,
                 GG.y + bG.y + xv * wG.y, GO.y + bO.y + xv * wO.y, cc.y, h1v);
    cn.z = cellc(GI.z + bI.z + xv * wI.z, GF.z + bF.z + xv * wF.z,
                 GG.z + bG.z + xv * wG.z, GO.z + bO.z + xv * wO.z, cc.z, h2v);
    cn.w = cellc(GI.w + bI.w + xv * wI.w, GF.w + bF.w + xv * wF.w,
                 GG.w + bG.w + xv * wG.w, GO.w + bO.w + xv * wO.w, cc.w, h3v);
    *(float4*)(c + (size_t)br * 1024 + u0) = cn;

    // packed h store: hP[rg][kc][q*16+m][j]
    {
        const int rg = br >> 4, ml = br & 15;
        const int kc = u0 >> 5, qq = (u0 >> 3) & 3, jo = u0 & 7;
        ushort4 hu;
        hu.x = f2bf(h0v); hu.y = f2bf(h1v); hu.z = f2bf(h2v); hu.w = f2bf(h3v);
        *(ushort4*)(hout + ((size_t)(rg * 32 + kc) * 64 + qq * 16 + ml) * 8 + jo) = hu;
    }

    if (fcW) {
        float4 fw = *(const float4*)(fcW + u0);
        float fcp = h0v * fw.x + h1v * fw.y + h2v * fw.z + h3v * fw.w;
        red[uq * 128 + lrow] = fcp;
        __syncthreads();
        if (tid < 128) {
            float s = red[tid] + red[128 + tid] + red[256 + tid] + red[384 + tid];
            if (ub == 0) s += fcb[0];
            atomicAdd(yout + (size_t)(mb + tid) * 96, s);
        }
        if (ydone) {
            __syncthreads();           // barrier drains this block's y atomics
            if (tid == 0) {
                __threadfence();
                atomicAdd(ydone, 1);
            }
        }
    }
}

// Encoder: blocks 0..127 layer0 step t; 128..255 layer1 step t-1 (pipelined).
__global__ __launch_bounds__(512)
__attribute__((amdgpu_waves_per_eu(2, 2)))
void k_enc_step(
    int t,
    const float* __restrict__ x,
    const float* __restrict__ Wih0, const float* __restrict__ b0,
    const unsigned short* __restrict__ Wenc0,
    const unsigned short* __restrict__ Wenc1, const float* __restrict__ b1,
    unsigned short* h0a, unsigned short* h0b,
    unsigned short* h1a, unsigned short* h1b,
    float* c0, float* c1)
{
    unsigned short* h0[2] = {h0a, h0b};
    unsigned short* h1[2] = {h1a, h1b};
    const int blk = blockIdx.x;
    if (blk < 128) {
        if (t >= 336) return;
        lstm_tile<1024>(blk, h0[(t + 1) & 1], nullptr, Wenc0, b0,
                        x + t, 336, Wih0, c0, h0[t & 1],
                        nullptr, nullptr, nullptr, nullptr, 0, nullptr);
    } else {
        const int u = t - 1;
        if (u < 0) return;
        lstm_tile<2048>(blk - 128, h0[u & 1], h1[(u + 1) & 1], Wenc1, b1,
                        nullptr, 0, nullptr, c1, h1[u & 1],
                        nullptr, nullptr, nullptr, nullptr, 0, nullptr);
    }
}

// Fused decoder: blocks 0..127 layer0 step i; 128..255 layer1 step i-1.
// Layer0 needs y[i-1] only in its EPILOGUE (x enters via Wih0), so it runs its
// GEMM concurrently with layer1's and spin-waits on done[i-1] (128 producer
// blocks). waves_per_eu(2,2) -> exactly 1 block/CU -> 256 blocks co-resident
// on 256 CUs -> the intra-launch wait cannot deadlock.
__global__ __launch_bounds__(512)
__attribute__((amdgpu_waves_per_eu(2, 2)))
void k_dec(
    int i,
    const float* __restrict__ x,
    float* __restrict__ dout,
    const float* __restrict__ dWih0, const float* __restrict__ db0,
    const unsigned short* __restrict__ Wdec0,
    const unsigned short* __restrict__ Wdec1, const float* __restrict__ db1,
    unsigned short* h0a, unsigned short* h0b,
    unsigned short* h1a, unsigned short* h1b,
    float* c0, float* c1,
    const float* __restrict__ fcW, const float* __restrict__ fcb,
    int* done)
{
    unsigned short* h0[2] = {h0a, h0b};
    unsigned short* h1[2] = {h1a, h1b};
    const int blk = blockIdx.x;
    if (blk < 128) {
        if (i >= 96) return;
        const int s = i;
        const float* xv; int xs; const int* xd = nullptr;
        if (s == 0) { xv = x + 335; xs = 336; }
        else        { xv = dout + (s - 1); xs = 96; xd = done + (s - 1); }
        lstm_tile<1024>(blk, h0[(s + 1) & 1], nullptr, Wdec0, db0,
                        xv, xs, dWih0, c0, h0[s & 1],
                        nullptr, nullptr, nullptr, xd, 128, nullptr);
    } else {
        const int s = i - 1;
        if (s < 0) return;
        lstm_tile<2048>(blk - 128, h0[s & 1], h1[(s + 1) & 1], Wdec1, db1,
                        nullptr, 0, nullptr, c1, h1[s & 1],
                        fcW, fcb, dout + s, nullptr, 0, done + s);
    }
}

// ---- prep: pack fp32 weights into WP fragment order (bf16) ----
template<int K>
__global__ void k_packW(const float* __restrict__ srcA, const float* __restrict__ srcB,
                        unsigned short* __restrict__ dst)
{
    constexpr int KC = K / 32;
    const int total = 4096 * K / 8;
    const int du = blockIdx.x * blockDim.x + threadIdx.x;
    if (du >= total) return;
    const int lane = du & 63;
    int rest = du >> 6;
    const int gate = rest & 3; rest >>= 2;
    const int kc = rest % KC;
    const int ug = rest / KC;
    const int q = lane >> 4, m = lane & 15;
    const int row = gate * 1024 + ug * 16 + m;
    const int k = kc * 32 + q * 8;
    const float* s;
    if (K == 2048 && k >= 1024) s = srcB + (size_t)row * 1024 + (k - 1024);
    else                        s = srcA + (size_t)row * 1024 + k;
    const float4 v0 = *(const float4*)(s);
    const float4 v1 = *(const float4*)(s + 4);
    short8 o;
    o[0] = (short)f2bf(v0.x); o[1] = (short)f2bf(v0.y);
    o[2] = (short)f2bf(v0.z); o[3] = (short)f2bf(v0.w);
    o[4] = (short)f2bf(v1.x); o[5] = (short)f2bf(v1.y);
    o[6] = (short)f2bf(v1.z); o[7] = (short)f2bf(v1.w);
    *(short8*)(dst + (size_t)du * 8) = o;
}

extern "C" void kernel_launch(void* const* d_in, const int* in_sizes, int n_in,
                              void* d_out, int out_size, void* d_ws, size_t ws_size,
                              hipStream_t stream)
{
    const float* x     = (const float*)d_in[0];
    const float* eWih0 = (const float*)d_in[1];
    const float* eWhh0 = (const float*)d_in[2];
    const float* eb0   = (const float*)d_in[3];
    const float* eWih1 = (const float*)d_in[4];
    const float* eWhh1 = (const float*)d_in[5];
    const float* eb1   = (const float*)d_in[6];
    const float* dWih0 = (const float*)d_in[7];
    const float* dWhh0 = (const float*)d_in[8];
    const float* db0   = (const float*)d_in[9];
    const float* dWih1 = (const float*)d_in[10];
    const float* dWhh1 = (const float*)d_in[11];
    const float* db1   = (const float*)d_in[12];
    const float* fcW   = (const float*)d_in[13];
    const float* fcb   = (const float*)d_in[14];
    float* out = (float*)d_out;

    char* ws = (char*)d_ws;
    size_t off = 0;
    auto walloc = [&](size_t bytes) -> void* {
        void* p = ws + off;
        off = (off + bytes + 255) & ~(size_t)255;
        return p;
    };
    unsigned short* Wenc0 = (unsigned short*)walloc((size_t)4096 * 1024 * 2 + 32768);
    unsigned short* Wenc1 = (unsigned short*)walloc((size_t)4096 * 2048 * 2 + 32768);
    unsigned short* Wdec0 = (unsigned short*)walloc((size_t)4096 * 1024 * 2 + 32768);
    unsigned short* Wdec1 = (unsigned short*)walloc((size_t)4096 * 2048 * 2 + 32768);
    const size_t STATE = (size_t)4 * 524288 + (size_t)2 * 1048576;
    char* stateBase = (char*)walloc(STATE + 65536);   // + guard for prefetch overrun
    unsigned short* h0a = (unsigned short*)(stateBase);
    unsigned short* h0b = (unsigned short*)(stateBase + 524288);
    unsigned short* h1a = (unsigned short*)(stateBase + 2 * 524288);
    unsigned short* h1b = (unsigned short*)(stateBase + 3 * 524288);
    float* c0 = (float*)(stateBase + 4 * 524288);
    float* c1 = (float*)(stateBase + 4 * 524288 + 1048576);
    int* done = (int*)walloc(4096);   // decoder y-completion counters [96]

    hipMemsetAsync(stateBase, 0, STATE, stream);
    hipMemsetAsync(done, 0, 4096, stream);
    hipMemsetAsync(d_out, 0, (size_t)out_size * sizeof(float), stream);

    {
        const int n1 = 4096 * 1024 / 8;
        const int n2 = 4096 * 2048 / 8;
        k_packW<1024><<<n1 / 256, 256, 0, stream>>>(eWhh0, nullptr, Wenc0);
        k_packW<1024><<<n1 / 256, 256, 0, stream>>>(dWhh0, nullptr, Wdec0);
        k_packW<2048><<<n2 / 256, 256, 0, stream>>>(eWih1, eWhh1, Wenc1);
        k_packW<2048><<<n2 / 256, 256, 0, stream>>>(dWih1, dWhh1, Wdec1);
    }

    for (int t = 0; t <= 336; ++t) {
        k_enc_step<<<256, 512, SMEM_BYTES, stream>>>(t, x, eWih0, eb0, Wenc0, Wenc1, eb1,
                                                     h0a, h0b, h1a, h1b, c0, c1);
    }
    for (int i = 0; i <= 96; ++i) {
        k_dec<<<256, 512, SMEM_BYTES, stream>>>(i, x, out, dWih0, db0, Wdec0, Wdec1, db1,
                                                h0a, h0b, h1a, h1b, c0, c1, fcW, fcb, done);
    }
}

// Round 2
// 15111.276 us; speedup vs baseline: 1.5351x; 1.5351x over previous
//
#include <hip/hip_runtime.h>

typedef short short8 __attribute__((ext_vector_type(8)));
typedef float f32x4 __attribute__((ext_vector_type(4)));

#define SMEM_BYTES (2*64*68*4 + 4*64*4)   // two 64x68 f32 tiles + 4x64 fc-reduce

__device__ __forceinline__ unsigned short f2bf(float x) {
    unsigned int u = __float_as_uint(x);
    u += 0x7FFFu + ((u >> 16) & 1u);   // round-to-nearest-even
    return (unsigned short)(u >> 16);
}

__device__ __forceinline__ float sigmoidf_(float x) {
    return 1.0f / (1.0f + __expf(-x));
}

__device__ __forceinline__ float tanhf_(float x) {
    float ax = fabsf(x);
    float e = __expf(2.0f * ax);
    float t = 1.0f - 2.0f / (e + 1.0f);
    return copysignf(t, x);
}

// ---------------- packed layouts ----------------
// hP  [rg 16][kc 32][lane 64][j 8]  (lane = q*16+m holds h[rg*16+m][kc*32+q*8+j])
// WP  [ug 64][kc K/32][gate 4][lane 64][j 8]
// Every K-loop load is base + lane*16B -> one contiguous 1 KB per instruction.

// One LSTM step tile: 64 batch rows x 16 units (x4 gates).
// 4 waves K-split, 4x4 MFMA register blocking, 4-stage register pipeline
// (needs ~224 VGPRs -> kernels use amdgpu_waves_per_eu(2,2) so the allocator
// doesn't collapse the pipeline; R4 profile showed it clamps to 128 otherwise).
// Prefetch overruns up to 3 chunks past the slice end -> guard memory required.
//
// xdone/xneed: optional device-scope spin (epilogue only) so a fused launch can
// consume y produced by sibling blocks of the SAME launch (decoder pipelining).
// ydone: bumped once per block after this block's fc atomics are drained.
template<int K>
__device__ __forceinline__ void lstm_tile(
    int idx,
    const unsigned short* __restrict__ A1,   // hP, first K-half
    const unsigned short* __restrict__ A2,   // hP, second K-half (K==2048) or null
    const unsigned short* __restrict__ W,    // WP packed
    const float* __restrict__ bias,          // [4096]
    const float* __restrict__ xvec, int xstride,
    const float* __restrict__ Wx,            // [4096] or null
    float* __restrict__ c,                   // [256,1024] fp32 in-place
    unsigned short* __restrict__ hout,       // hP packed out
    const float* __restrict__ fcW,
    const float* __restrict__ fcb,
    float* __restrict__ yout,
    const int* xdone, int xneed, int* ydone)
{
    extern __shared__ float smem[];
    float* T0  = smem;                 // 64 x 68
    float* T1  = smem + 64 * 68;
    float* red = smem + 2 * 64 * 68;   // 4 x 64

    constexpr int KS = K / 4;
    constexpr int NC = KS / 32;        // chunks per wave (8 or 16)
    constexpr int KC = K / 32;
    const int tid  = threadIdx.x;
    const int lane = tid & 63;
    const int wave = tid >> 6;
    const int g  = idx >> 6;           // batch group (64 rows)
    const int ug = idx & 63;           // unit group (16 units)
    const int mb = g * 64;
    const int ub = ug * 16;

    const unsigned short* Af = (K == 1024) ? A1 : (wave < 2 ? A1 : A2);
    const int kcA0 = (wave * NC) & 31;
    const int kcW0 = wave * NC;
    const unsigned short* ap = Af + ((size_t)(g * 4) * 32 + kcA0) * 512 + lane * 8;
    const unsigned short* bp = W + ((size_t)(ug * KC + kcW0) * 4) * 512 + lane * 8;

    f32x4 acc[4][4];
#pragma unroll
    for (int i = 0; i < 4; ++i)
#pragma unroll
        for (int j = 0; j < 4; ++j) acc[i][j] = (f32x4){0.f, 0.f, 0.f, 0.f};

    short8 aS[4][4], bS[4][4];
    auto LD = [&](int s, int cc) {
#pragma unroll
        for (int mi = 0; mi < 4; ++mi)
            aS[s][mi] = *(const short8*)(ap + mi * 16384 + cc * 512);
#pragma unroll
        for (int gt = 0; gt < 4; ++gt)
            bS[s][gt] = *(const short8*)(bp + (cc * 4 + gt) * 512);
    };
    auto MM = [&](int s) {
#pragma unroll
        for (int mi = 0; mi < 4; ++mi)
#pragma unroll
            for (int gt = 0; gt < 4; ++gt)
                acc[mi][gt] = __builtin_amdgcn_mfma_f32_16x16x32_bf16(
                    aS[s][mi], bS[s][gt], acc[mi][gt], 0, 0, 0);
    };

    LD(0, 0); LD(1, 1); LD(2, 2); LD(3, 3);
#pragma unroll
    for (int cc = 0; cc < NC; cc += 4) {
        MM(0); LD(0, cc + 4);    // tail iters overrun into guard memory
        MM(1); LD(1, cc + 5);
        MM(2); LD(2, cc + 6);
        MM(3); LD(3, cc + 7);
    }

    // ---- K-split reduction through LDS ----
    const int q = lane >> 4;
    const int m = lane & 15;
    float* Tw = (wave & 1) ? T1 : T0;
    if (wave < 2) {
#pragma unroll
        for (int mi = 0; mi < 4; ++mi)
#pragma unroll
            for (int gt = 0; gt < 4; ++gt)
#pragma unroll
                for (int r = 0; r < 4; ++r)
                    Tw[(mi * 16 + q * 4 + r) * 68 + gt * 16 + m] = acc[mi][gt][r];
    }
    __syncthreads();
    if (wave >= 2) {
#pragma unroll
        for (int mi = 0; mi < 4; ++mi)
#pragma unroll
            for (int gt = 0; gt < 4; ++gt)
#pragma unroll
                for (int r = 0; r < 4; ++r)
                    Tw[(mi * 16 + q * 4 + r) * 68 + gt * 16 + m] += acc[mi][gt][r];
    }
    __syncthreads();

    // ---- epilogue: thread owns (row = tid>>2, units u0..u0+3) ----
    const int lrow = tid >> 2;
    const int uq   = tid & 3;
    const int br   = mb + lrow;
    const int u0   = ub + uq * 4;
    const int toff = lrow * 68 + uq * 4;

    auto gate4 = [&](int gofs) -> float4 {
        float4 a = *(const float4*)(T0 + toff + gofs);
        float4 b = *(const float4*)(T1 + toff + gofs);
        return make_float4(a.x + b.x, a.y + b.y, a.z + b.z, a.w + b.w);
    };
    float4 GI = gate4(0), GF = gate4(16), GG = gate4(32), GO = gate4(48);
    float4 bI = *(const float4*)(bias + u0);
    float4 bF = *(const float4*)(bias + 1024 + u0);
    float4 bG = *(const float4*)(bias + 2048 + u0);
    float4 bO = *(const float4*)(bias + 3072 + u0);
    float4 wI = {0,0,0,0}, wF = {0,0,0,0}, wG = {0,0,0,0}, wO = {0,0,0,0};
    float xv = 0.f;
    if (xvec) {
        if (xdone) {
            // y[s-1] is produced by sibling blocks of this launch; wait for all
            // producer blocks, then read coherently (device-scope load bypasses
            // potentially-stale L1 line).
            if (tid == 0) {
                while (__hip_atomic_load(xdone, __ATOMIC_ACQUIRE,
                                         __HIP_MEMORY_SCOPE_AGENT) < xneed)
                    __builtin_amdgcn_s_sleep(8);
            }
            __syncthreads();
            xv = __hip_atomic_load(xvec + (size_t)br * xstride,
                                   __ATOMIC_RELAXED, __HIP_MEMORY_SCOPE_AGENT);
        } else {
            xv = xvec[(size_t)br * xstride];
        }
        wI = *(const float4*)(Wx + u0);
        wF = *(const float4*)(Wx + 1024 + u0);
        wG = *(const float4*)(Wx + 2048 + u0);
        wO = *(const float4*)(Wx + 3072 + u0);
    }
    float4 cc = *(const float4*)(c + (size_t)br * 1024 + u0);

    auto cellc = [&](float gi, float gf, float gg, float go, float cold, float& hO) -> float {
        float i = sigmoidf_(gi);
        float f = sigmoidf_(gf);
        float o = sigmoidf_(go);
        float cn = f * cold + i * tanhf_(gg);
        hO = o * tanhf_(cn);
        return cn;
    };
    float h0v, h1v, h2v, h3v;
    float4 cn;
    cn.x = cellc(GI.x + bI.x + xv * wI.x, GF.x + bF.x + xv * wF.x,
                 GG.x + bG.x + xv * wG.x, GO.x + bO.x + xv * wO.x, cc.x, h0v);
    cn.y = cellc(GI.y + bI.y + xv * wI.y, GF.y + bF.y + xv * wF.y,
                 GG.y + bG.y + xv * wG.y, GO.y + bO.y + xv * wO.y, cc.y, h1v);
    cn.z = cellc(GI.z + bI.z + xv * wI.z, GF.z + bF.z + xv * wF.z,
                 GG.z + bG.z + xv * wG.z, GO.z + bO.z + xv * wO.z, cc.z, h2v);
    cn.w = cellc(GI.w + bI.w + xv * wI.w, GF.w + bF.w + xv * wF.w,
                 GG.w + bG.w + xv * wG.w, GO.w + bO.w + xv * wO.w, cc.w, h3v);
    *(float4*)(c + (size_t)br * 1024 + u0) = cn;

    // packed h store: hP[rg][kc][q*16+m][j]
    {
        const int rg = br >> 4, ml = br & 15;
        const int kc = u0 >> 5, qq = (u0 >> 3) & 3, jo = u0 & 7;
        ushort4 hu;
        hu.x = f2bf(h0v); hu.y = f2bf(h1v); hu.z = f2bf(h2v); hu.w = f2bf(h3v);
        *(ushort4*)(hout + ((size_t)(rg * 32 + kc) * 64 + qq * 16 + ml) * 8 + jo) = hu;
    }

    if (fcW) {
        float4 fw = *(const float4*)(fcW + u0);
        float fcp = h0v * fw.x + h1v * fw.y + h2v * fw.z + h3v * fw.w;
        red[uq * 64 + lrow] = fcp;
        __syncthreads();
        if (tid < 64) {
            float s = red[tid] + red[64 + tid] + red[128 + tid] + red[192 + tid];
            if (ub == 0) s += fcb[0];
            atomicAdd(yout + (size_t)(mb + tid) * 96, s);
        }
        if (ydone) {
            __syncthreads();           // barrier drains this block's y atomics
            if (tid == 0) {
                __threadfence();
                atomicAdd(ydone, 1);
            }
        }
    }
}

// Encoder: blocks 0..255 layer0 step t; 256..511 layer1 step t-1 (pipelined).
__global__ __launch_bounds__(256)
__attribute__((amdgpu_waves_per_eu(2, 2)))
void k_enc_step(
    int t,
    const float* __restrict__ x,
    const float* __restrict__ Wih0, const float* __restrict__ b0,
    const unsigned short* __restrict__ Wenc0,
    const unsigned short* __restrict__ Wenc1, const float* __restrict__ b1,
    unsigned short* h0a, unsigned short* h0b,
    unsigned short* h1a, unsigned short* h1b,
    float* c0, float* c1)
{
    unsigned short* h0[2] = {h0a, h0b};
    unsigned short* h1[2] = {h1a, h1b};
    const int blk = blockIdx.x;
    if (blk < 256) {
        if (t >= 336) return;
        lstm_tile<1024>(blk, h0[(t + 1) & 1], nullptr, Wenc0, b0,
                        x + t, 336, Wih0, c0, h0[t & 1],
                        nullptr, nullptr, nullptr, nullptr, 0, nullptr);
    } else {
        const int u = t - 1;
        if (u < 0) return;
        lstm_tile<2048>(blk - 256, h0[u & 1], h1[(u + 1) & 1], Wenc1, b1,
                        nullptr, 0, nullptr, c1, h1[u & 1],
                        nullptr, nullptr, nullptr, nullptr, 0, nullptr);
    }
}

// Fused decoder: blocks 0..255 layer0 step i; 256..511 layer1 step i-1.
// Layer0 needs y[i-1] only in its EPILOGUE (x enters via Wih0), so its GEMM
// runs concurrently with layer1's; the epilogue spin-waits on done[i-1]
// (256 producer blocks). All 512 blocks fit co-resident (2 blocks/CU at
// waves_per_eu(2,2)), so the intra-launch wait cannot deadlock.
__global__ __launch_bounds__(256)
__attribute__((amdgpu_waves_per_eu(2, 2)))
void k_dec(
    int i,
    const float* __restrict__ x,
    float* __restrict__ dout,
    const float* __restrict__ dWih0, const float* __restrict__ db0,
    const unsigned short* __restrict__ Wdec0,
    const unsigned short* __restrict__ Wdec1, const float* __restrict__ db1,
    unsigned short* h0a, unsigned short* h0b,
    unsigned short* h1a, unsigned short* h1b,
    float* c0, float* c1,
    const float* __restrict__ fcW, const float* __restrict__ fcb,
    int* done)
{
    unsigned short* h0[2] = {h0a, h0b};
    unsigned short* h1[2] = {h1a, h1b};
    const int blk = blockIdx.x;
    if (blk < 256) {
        if (i >= 96) return;
        const int s = i;
        const float* xv; int xs; const int* xd = nullptr;
        if (s == 0) { xv = x + 335; xs = 336; }
        else        { xv = dout + (s - 1); xs = 96; xd = done + (s - 1); }
        lstm_tile<1024>(blk, h0[(s + 1) & 1], nullptr, Wdec0, db0,
                        xv, xs, dWih0, c0, h0[s & 1],
                        nullptr, nullptr, nullptr, xd, 256, nullptr);
    } else {
        const int s = i - 1;
        if (s < 0) return;
        lstm_tile<2048>(blk - 256, h0[s & 1], h1[(s + 1) & 1], Wdec1, db1,
                        nullptr, 0, nullptr, c1, h1[s & 1],
                        fcW, fcb, dout + s, nullptr, 0, done + s);
    }
}

// ---- prep: pack fp32 weights into WP fragment order (bf16) ----
template<int K>
__global__ void k_packW(const float* __restrict__ srcA, const float* __restrict__ srcB,
                        unsigned short* __restrict__ dst)
{
    constexpr int KC = K / 32;
    const int total = 4096 * K / 8;
    const int du = blockIdx.x * blockDim.x + threadIdx.x;
    if (du >= total) return;
    const int lane = du & 63;
    int rest = du >> 6;
    const int gate = rest & 3; rest >>= 2;
    const int kc = rest % KC;
    const int ug = rest / KC;
    const int q = lane >> 4, m = lane & 15;
    const int row = gate * 1024 + ug * 16 + m;
    const int k = kc * 32 + q * 8;
    const float* s;
    if (K == 2048 && k >= 1024) s = srcB + (size_t)row * 1024 + (k - 1024);
    else                        s = srcA + (size_t)row * 1024 + k;
    const float4 v0 = *(const float4*)(s);
    const float4 v1 = *(const float4*)(s + 4);
    short8 o;
    o[0] = (short)f2bf(v0.x); o[1] = (short)f2bf(v0.y);
    o[2] = (short)f2bf(v0.z); o[3] = (short)f2bf(v0.w);
    o[4] = (short)f2bf(v1.x); o[5] = (short)f2bf(v1.y);
    o[6] = (short)f2bf(v1.z); o[7] = (short)f2bf(v1.w);
    *(short8*)(dst + (size_t)du * 8) = o;
}

extern "C" void kernel_launch(void* const* d_in, const int* in_sizes, int n_in,
                              void* d_out, int out_size, void* d_ws, size_t ws_size,
                              hipStream_t stream)
{
    const float* x     = (const float*)d_in[0];
    const float* eWih0 = (const float*)d_in[1];
    const float* eWhh0 = (const float*)d_in[2];
    const float* eb0   = (const float*)d_in[3];
    const float* eWih1 = (const float*)d_in[4];
    const float* eWhh1 = (const float*)d_in[5];
    const float* eb1   = (const float*)d_in[6];
    const float* dWih0 = (const float*)d_in[7];
    const float* dWhh0 = (const float*)d_in[8];
    const float* db0   = (const float*)d_in[9];
    const float* dWih1 = (const float*)d_in[10];
    const float* dWhh1 = (const float*)d_in[11];
    const float* db1   = (const float*)d_in[12];
    const float* fcW   = (const float*)d_in[13];
    const float* fcb   = (const float*)d_in[14];
    float* out = (float*)d_out;

    char* ws = (char*)d_ws;
    size_t off = 0;
    auto walloc = [&](size_t bytes) -> void* {
        void* p = ws + off;
        off = (off + bytes + 255) & ~(size_t)255;
        return p;
    };
    unsigned short* Wenc0 = (unsigned short*)walloc((size_t)4096 * 1024 * 2 + 32768);
    unsigned short* Wenc1 = (unsigned short*)walloc((size_t)4096 * 2048 * 2 + 32768);
    unsigned short* Wdec0 = (unsigned short*)walloc((size_t)4096 * 1024 * 2 + 32768);
    unsigned short* Wdec1 = (unsigned short*)walloc((size_t)4096 * 2048 * 2 + 32768);
    const size_t STATE = (size_t)4 * 524288 + (size_t)2 * 1048576;
    char* stateBase = (char*)walloc(STATE + 65536);   // + guard for prefetch overrun
    unsigned short* h0a = (unsigned short*)(stateBase);
    unsigned short* h0b = (unsigned short*)(stateBase + 524288);
    unsigned short* h1a = (unsigned short*)(stateBase + 2 * 524288);
    unsigned short* h1b = (unsigned short*)(stateBase + 3 * 524288);
    float* c0 = (float*)(stateBase + 4 * 524288);
    float* c1 = (float*)(stateBase + 4 * 524288 + 1048576);
    int* done = (int*)walloc(4096);   // decoder y-completion counters [96]

    hipMemsetAsync(stateBase, 0, STATE, stream);
    hipMemsetAsync(done, 0, 4096, stream);
    hipMemsetAsync(d_out, 0, (size_t)out_size * sizeof(float), stream);

    {
        const int n1 = 4096 * 1024 / 8;
        const int n2 = 4096 * 2048 / 8;
        k_packW<1024><<<n1 / 256, 256, 0, stream>>>(eWhh0, nullptr, Wenc0);
        k_packW<1024><<<n1 / 256, 256, 0, stream>>>(dWhh0, nullptr, Wdec0);
        k_packW<2048><<<n2 / 256, 256, 0, stream>>>(eWih1, eWhh1, Wenc1);
        k_packW<2048><<<n2 / 256, 256, 0, stream>>>(dWih1, dWhh1, Wdec1);
    }

    for (int t = 0; t <= 336; ++t) {
        k_enc_step<<<512, 256, SMEM_BYTES, stream>>>(t, x, eWih0, eb0, Wenc0, Wenc1, eb1,
                                                     h0a, h0b, h1a, h1b, c0, c1);
    }
    for (int i = 0; i <= 96; ++i) {
        k_dec<<<512, 256, SMEM_BYTES, stream>>>(i, x, out, dWih0, db0, Wdec0, Wdec1, db1,
                                                h0a, h0b, h1a, h1b, c0, c1, fcW, fcb, done);
    }
}

// Round 3
// 10743.681 us; speedup vs baseline: 2.1592x; 1.4065x over previous
//
#include <hip/hip_runtime.h>

typedef short short8 __attribute__((ext_vector_type(8)));
typedef float f32x4 __attribute__((ext_vector_type(4)));

#define SMEM_BYTES (2*64*68*4 + 4*64*4)   // two 64x68 f32 tiles + 4x64 fc-reduce

__device__ __forceinline__ unsigned short f2bf(float x) {
    unsigned int u = __float_as_uint(x);
    u += 0x7FFFu + ((u >> 16) & 1u);   // round-to-nearest-even
    return (unsigned short)(u >> 16);
}

__device__ __forceinline__ float sigmoidf_(float x) {
    return 1.0f / (1.0f + __expf(-x));
}

__device__ __forceinline__ float tanhf_(float x) {
    float ax = fabsf(x);
    float e = __expf(2.0f * ax);
    float t = 1.0f - 2.0f / (e + 1.0f);
    return copysignf(t, x);
}

// ---------------- packed layouts ----------------
// hP  [rg 16][kc 32][lane 64][j 8]  (lane = q*16+m holds h[rg*16+m][kc*32+q*8+j])
// WP  [ug 64][kc K/32][gate 4][lane 64][j 8]
// Every K-loop load is base + lane*16B -> one contiguous 1 KB per instruction.

// One LSTM step tile: 64 batch rows x 16 units (x4 gates).
// 4 waves K-split, 4x4 MFMA register blocking, 4-stage register pipeline
// (needs ~224 VGPRs -> kernels use amdgpu_waves_per_eu(2,2) so the allocator
// doesn't collapse the pipeline).
// Prefetch overruns up to 3 chunks past the slice end -> guard memory required.
//
// xdone/xneed: optional intra-launch producer flag (epilogue only). The spin
// MUST poll with RELAXED agent-scope loads: an ACQUIRE at agent scope
// invalidates the XCD's (non-coherent) L2 every iteration — R2 measured that
// as a ~7x decoder blowup. Relaxed agent atomic loads read the coherence
// point directly (that's why the spin observes the update), and the y values
// are themselves read as relaxed agent atomics, so no acquire is needed.
// ydone: bumped once per block after this block's fc atomics are drained.
template<int K>
__device__ __forceinline__ void lstm_tile(
    int idx,
    const unsigned short* __restrict__ A1,   // hP, first K-half
    const unsigned short* __restrict__ A2,   // hP, second K-half (K==2048) or null
    const unsigned short* __restrict__ W,    // WP packed
    const float* __restrict__ bias,          // [4096]
    const float* __restrict__ xvec, int xstride,
    const float* __restrict__ Wx,            // [4096] or null
    float* __restrict__ c,                   // [256,1024] fp32 in-place
    unsigned short* __restrict__ hout,       // hP packed out
    const float* __restrict__ fcW,
    const float* __restrict__ fcb,
    float* __restrict__ yout,
    const int* xdone, int xneed, int* ydone)
{
    extern __shared__ float smem[];
    float* T0  = smem;                 // 64 x 68
    float* T1  = smem + 64 * 68;
    float* red = smem + 2 * 64 * 68;   // 4 x 64

    constexpr int KS = K / 4;
    constexpr int NC = KS / 32;        // chunks per wave (8 or 16)
    constexpr int KC = K / 32;
    const int tid  = threadIdx.x;
    const int lane = tid & 63;
    const int wave = tid >> 6;
    const int g  = idx >> 6;           // batch group (64 rows)
    const int ug = idx & 63;           // unit group (16 units)
    const int mb = g * 64;
    const int ub = ug * 16;

    const unsigned short* Af = (K == 1024) ? A1 : (wave < 2 ? A1 : A2);
    const int kcA0 = (wave * NC) & 31;
    const int kcW0 = wave * NC;
    const unsigned short* ap = Af + ((size_t)(g * 4) * 32 + kcA0) * 512 + lane * 8;
    const unsigned short* bp = W + ((size_t)(ug * KC + kcW0) * 4) * 512 + lane * 8;

    f32x4 acc[4][4];
#pragma unroll
    for (int i = 0; i < 4; ++i)
#pragma unroll
        for (int j = 0; j < 4; ++j) acc[i][j] = (f32x4){0.f, 0.f, 0.f, 0.f};

    short8 aS[4][4], bS[4][4];
    auto LD = [&](int s, int cc) {
#pragma unroll
        for (int mi = 0; mi < 4; ++mi)
            aS[s][mi] = *(const short8*)(ap + mi * 16384 + cc * 512);
#pragma unroll
        for (int gt = 0; gt < 4; ++gt)
            bS[s][gt] = *(const short8*)(bp + (cc * 4 + gt) * 512);
    };
    auto MM = [&](int s) {
#pragma unroll
        for (int mi = 0; mi < 4; ++mi)
#pragma unroll
            for (int gt = 0; gt < 4; ++gt)
                acc[mi][gt] = __builtin_amdgcn_mfma_f32_16x16x32_bf16(
                    aS[s][mi], bS[s][gt], acc[mi][gt], 0, 0, 0);
    };

    LD(0, 0); LD(1, 1); LD(2, 2); LD(3, 3);
#pragma unroll
    for (int cc = 0; cc < NC; cc += 4) {
        MM(0); LD(0, cc + 4);    // tail iters overrun into guard memory
        MM(1); LD(1, cc + 5);
        MM(2); LD(2, cc + 6);
        MM(3); LD(3, cc + 7);
    }

    // ---- K-split reduction through LDS ----
    const int q = lane >> 4;
    const int m = lane & 15;
    float* Tw = (wave & 1) ? T1 : T0;
    if (wave < 2) {
#pragma unroll
        for (int mi = 0; mi < 4; ++mi)
#pragma unroll
            for (int gt = 0; gt < 4; ++gt)
#pragma unroll
                for (int r = 0; r < 4; ++r)
                    Tw[(mi * 16 + q * 4 + r) * 68 + gt * 16 + m] = acc[mi][gt][r];
    }
    __syncthreads();
    if (wave >= 2) {
#pragma unroll
        for (int mi = 0; mi < 4; ++mi)
#pragma unroll
            for (int gt = 0; gt < 4; ++gt)
#pragma unroll
                for (int r = 0; r < 4; ++r)
                    Tw[(mi * 16 + q * 4 + r) * 68 + gt * 16 + m] += acc[mi][gt][r];
    }
    __syncthreads();

    // ---- epilogue: thread owns (row = tid>>2, units u0..u0+3) ----
    const int lrow = tid >> 2;
    const int uq   = tid & 3;
    const int br   = mb + lrow;
    const int u0   = ub + uq * 4;
    const int toff = lrow * 68 + uq * 4;

    auto gate4 = [&](int gofs) -> float4 {
        float4 a = *(const float4*)(T0 + toff + gofs);
        float4 b = *(const float4*)(T1 + toff + gofs);
        return make_float4(a.x + b.x, a.y + b.y, a.z + b.z, a.w + b.w);
    };
    float4 GI = gate4(0), GF = gate4(16), GG = gate4(32), GO = gate4(48);
    float4 bI = *(const float4*)(bias + u0);
    float4 bF = *(const float4*)(bias + 1024 + u0);
    float4 bG = *(const float4*)(bias + 2048 + u0);
    float4 bO = *(const float4*)(bias + 3072 + u0);
    float4 wI = {0,0,0,0}, wF = {0,0,0,0}, wG = {0,0,0,0}, wO = {0,0,0,0};
    float xv = 0.f;
    if (xvec) {
        if (xdone) {
            // Spin with RELAXED agent loads (no per-iteration L2 invalidate).
            if (tid == 0) {
                while (__hip_atomic_load(xdone, __ATOMIC_RELAXED,
                                         __HIP_MEMORY_SCOPE_AGENT) < xneed)
                    __builtin_amdgcn_s_sleep(2);
            }
            __syncthreads();
            // y read as agent-scope atomic -> fetched from the coherence
            // point (producer published with threadfence before the flag).
            xv = __hip_atomic_load(xvec + (size_t)br * xstride,
                                   __ATOMIC_RELAXED, __HIP_MEMORY_SCOPE_AGENT);
        } else {
            xv = xvec[(size_t)br * xstride];
        }
        wI = *(const float4*)(Wx + u0);
        wF = *(const float4*)(Wx + 1024 + u0);
        wG = *(const float4*)(Wx + 2048 + u0);
        wO = *(const float4*)(Wx + 3072 + u0);
    }
    float4 cc = *(const float4*)(c + (size_t)br * 1024 + u0);

    auto cellc = [&](float gi, float gf, float gg, float go, float cold, float& hO) -> float {
        float i = sigmoidf_(gi);
        float f = sigmoidf_(gf);
        float o = sigmoidf_(go);
        float cn = f * cold + i * tanhf_(gg);
        hO = o * tanhf_(cn);
        return cn;
    };
    float h0v, h1v, h2v, h3v;
    float4 cn;
    cn.x = cellc(GI.x + bI.x + xv * wI.x, GF.x + bF.x + xv * wF.x,
                 GG.x + bG.x + xv * wG.x, GO.x + bO.x + xv * wO.x, cc.x, h0v);
    cn.y = cellc(GI.y + bI.y + xv * wI.y, GF.y + bF.y + xv * wF.y,
                 GG.y + bG.y + xv * wG.y, GO.y + bO.y + xv * wO.y, cc.y, h1v);
    cn.z = cellc(GI.z + bI.z + xv * wI.z, GF.z + bF.z + xv * wF.z,
                 GG.z + bG.z + xv * wG.z, GO.z + bO.z + xv * wO.z, cc.z, h2v);
    cn.w = cellc(GI.w + bI.w + xv * wI.w, GF.w + bF.w + xv * wF.w,
                 GG.w + bG.w + xv * wG.w, GO.w + bO.w + xv * wO.w, cc.w, h3v);
    *(float4*)(c + (size_t)br * 1024 + u0) = cn;

    // packed h store: hP[rg][kc][q*16+m][j]
    {
        const int rg = br >> 4, ml = br & 15;
        const int kc = u0 >> 5, qq = (u0 >> 3) & 3, jo = u0 & 7;
        ushort4 hu;
        hu.x = f2bf(h0v); hu.y = f2bf(h1v); hu.z = f2bf(h2v); hu.w = f2bf(h3v);
        *(ushort4*)(hout + ((size_t)(rg * 32 + kc) * 64 + qq * 16 + ml) * 8 + jo) = hu;
    }

    if (fcW) {
        float4 fw = *(const float4*)(fcW + u0);
        float fcp = h0v * fw.x + h1v * fw.y + h2v * fw.z + h3v * fw.w;
        red[uq * 64 + lrow] = fcp;
        __syncthreads();
        if (tid < 64) {
            float s = red[tid] + red[64 + tid] + red[128 + tid] + red[192 + tid];
            if (ub == 0) s += fcb[0];
            atomicAdd(yout + (size_t)(mb + tid) * 96, s);
        }
        if (ydone) {
            __syncthreads();           // barrier drains this block's y atomics
            if (tid == 0) {
                __threadfence();
                atomicAdd(ydone, 1);
            }
        }
    }
}

// Encoder: blocks 0..255 layer0 step t; 256..511 layer1 step t-1 (pipelined).
__global__ __launch_bounds__(256)
__attribute__((amdgpu_waves_per_eu(2, 2)))
void k_enc_step(
    int t,
    const float* __restrict__ x,
    const float* __restrict__ Wih0, const float* __restrict__ b0,
    const unsigned short* __restrict__ Wenc0,
    const unsigned short* __restrict__ Wenc1, const float* __restrict__ b1,
    unsigned short* h0a, unsigned short* h0b,
    unsigned short* h1a, unsigned short* h1b,
    float* c0, float* c1)
{
    unsigned short* h0[2] = {h0a, h0b};
    unsigned short* h1[2] = {h1a, h1b};
    const int blk = blockIdx.x;
    if (blk < 256) {
        if (t >= 336) return;
        lstm_tile<1024>(blk, h0[(t + 1) & 1], nullptr, Wenc0, b0,
                        x + t, 336, Wih0, c0, h0[t & 1],
                        nullptr, nullptr, nullptr, nullptr, 0, nullptr);
    } else {
        const int u = t - 1;
        if (u < 0) return;
        lstm_tile<2048>(blk - 256, h0[u & 1], h1[(u + 1) & 1], Wenc1, b1,
                        nullptr, 0, nullptr, c1, h1[u & 1],
                        nullptr, nullptr, nullptr, nullptr, 0, nullptr);
    }
}

// Fused decoder: blocks 0..255 layer0 step i; 256..511 layer1 step i-1.
// Layer0 needs y[i-1] only in its EPILOGUE (x enters via Wih0), so its GEMM
// runs concurrently with layer1's; the epilogue spin-waits on done[i-1]
// (256 producer blocks). All 512 blocks fit co-resident (2 blocks/CU at
// waves_per_eu(2,2)), so the intra-launch wait cannot deadlock.
__global__ __launch_bounds__(256)
__attribute__((amdgpu_waves_per_eu(2, 2)))
void k_dec(
    int i,
    const float* __restrict__ x,
    float* __restrict__ dout,
    const float* __restrict__ dWih0, const float* __restrict__ db0,
    const unsigned short* __restrict__ Wdec0,
    const unsigned short* __restrict__ Wdec1, const float* __restrict__ db1,
    unsigned short* h0a, unsigned short* h0b,
    unsigned short* h1a, unsigned short* h1b,
    float* c0, float* c1,
    const float* __restrict__ fcW, const float* __restrict__ fcb,
    int* done)
{
    unsigned short* h0[2] = {h0a, h0b};
    unsigned short* h1[2] = {h1a, h1b};
    const int blk = blockIdx.x;
    if (blk < 256) {
        if (i >= 96) return;
        const int s = i;
        const float* xv; int xs; const int* xd = nullptr;
        if (s == 0) { xv = x + 335; xs = 336; }
        else        { xv = dout + (s - 1); xs = 96; xd = done + (s - 1); }
        lstm_tile<1024>(blk, h0[(s + 1) & 1], nullptr, Wdec0, db0,
                        xv, xs, dWih0, c0, h0[s & 1],
                        nullptr, nullptr, nullptr, xd, 256, nullptr);
    } else {
        const int s = i - 1;
        if (s < 0) return;
        lstm_tile<2048>(blk - 256, h0[s & 1], h1[(s + 1) & 1], Wdec1, db1,
                        nullptr, 0, nullptr, c1, h1[s & 1],
                        fcW, fcb, dout + s, nullptr, 0, done + s);
    }
}

// ---- prep: pack fp32 weights into WP fragment order (bf16) ----
template<int K>
__global__ void k_packW(const float* __restrict__ srcA, const float* __restrict__ srcB,
                        unsigned short* __restrict__ dst)
{
    constexpr int KC = K / 32;
    const int total = 4096 * K / 8;
    const int du = blockIdx.x * blockDim.x + threadIdx.x;
    if (du >= total) return;
    const int lane = du & 63;
    int rest = du >> 6;
    const int gate = rest & 3; rest >>= 2;
    const int kc = rest % KC;
    const int ug = rest / KC;
    const int q = lane >> 4, m = lane & 15;
    const int row = gate * 1024 + ug * 16 + m;
    const int k = kc * 32 + q * 8;
    const float* s;
    if (K == 2048 && k >= 1024) s = srcB + (size_t)row * 1024 + (k - 1024);
    else                        s = srcA + (size_t)row * 1024 + k;
    const float4 v0 = *(const float4*)(s);
    const float4 v1 = *(const float4*)(s + 4);
    short8 o;
    o[0] = (short)f2bf(v0.x); o[1] = (short)f2bf(v0.y);
    o[2] = (short)f2bf(v0.z); o[3] = (short)f2bf(v0.w);
    o[4] = (short)f2bf(v1.x); o[5] = (short)f2bf(v1.y);
    o[6] = (short)f2bf(v1.z); o[7] = (short)f2bf(v1.w);
    *(short8*)(dst + (size_t)du * 8) = o;
}

extern "C" void kernel_launch(void* const* d_in, const int* in_sizes, int n_in,
                              void* d_out, int out_size, void* d_ws, size_t ws_size,
                              hipStream_t stream)
{
    const float* x     = (const float*)d_in[0];
    const float* eWih0 = (const float*)d_in[1];
    const float* eWhh0 = (const float*)d_in[2];
    const float* eb0   = (const float*)d_in[3];
    const float* eWih1 = (const float*)d_in[4];
    const float* eWhh1 = (const float*)d_in[5];
    const float* eb1   = (const float*)d_in[6];
    const float* dWih0 = (const float*)d_in[7];
    const float* dWhh0 = (const float*)d_in[8];
    const float* db0   = (const float*)d_in[9];
    const float* dWih1 = (const float*)d_in[10];
    const float* dWhh1 = (const float*)d_in[11];
    const float* db1   = (const float*)d_in[12];
    const float* fcW   = (const float*)d_in[13];
    const float* fcb   = (const float*)d_in[14];
    float* out = (float*)d_out;

    char* ws = (char*)d_ws;
    size_t off = 0;
    auto walloc = [&](size_t bytes) -> void* {
        void* p = ws + off;
        off = (off + bytes + 255) & ~(size_t)255;
        return p;
    };
    unsigned short* Wenc0 = (unsigned short*)walloc((size_t)4096 * 1024 * 2 + 32768);
    unsigned short* Wenc1 = (unsigned short*)walloc((size_t)4096 * 2048 * 2 + 32768);
    unsigned short* Wdec0 = (unsigned short*)walloc((size_t)4096 * 1024 * 2 + 32768);
    unsigned short* Wdec1 = (unsigned short*)walloc((size_t)4096 * 2048 * 2 + 32768);
    const size_t STATE = (size_t)4 * 524288 + (size_t)2 * 1048576;
    char* stateBase = (char*)walloc(STATE + 65536);   // + guard for prefetch overrun
    unsigned short* h0a = (unsigned short*)(stateBase);
    unsigned short* h0b = (unsigned short*)(stateBase + 524288);
    unsigned short* h1a = (unsigned short*)(stateBase + 2 * 524288);
    unsigned short* h1b = (unsigned short*)(stateBase + 3 * 524288);
    float* c0 = (float*)(stateBase + 4 * 524288);
    float* c1 = (float*)(stateBase + 4 * 524288 + 1048576);
    int* done = (int*)walloc(4096);   // decoder y-completion counters [96]

    hipMemsetAsync(stateBase, 0, STATE, stream);
    hipMemsetAsync(done, 0, 4096, stream);
    hipMemsetAsync(d_out, 0, (size_t)out_size * sizeof(float), stream);

    {
        const int n1 = 4096 * 1024 / 8;
        const int n2 = 4096 * 2048 / 8;
        k_packW<1024><<<n1 / 256, 256, 0, stream>>>(eWhh0, nullptr, Wenc0);
        k_packW<1024><<<n1 / 256, 256, 0, stream>>>(dWhh0, nullptr, Wdec0);
        k_packW<2048><<<n2 / 256, 256, 0, stream>>>(eWih1, eWhh1, Wenc1);
        k_packW<2048><<<n2 / 256, 256, 0, stream>>>(dWih1, dWhh1, Wdec1);
    }

    for (int t = 0; t <= 336; ++t) {
        k_enc_step<<<512, 256, SMEM_BYTES, stream>>>(t, x, eWih0, eb0, Wenc0, Wenc1, eb1,
                                                     h0a, h0b, h1a, h1b, c0, c1);
    }
    for (int i = 0; i <= 96; ++i) {
        k_dec<<<512, 256, SMEM_BYTES, stream>>>(i, x, out, dWih0, db0, Wdec0, Wdec1, db1,
                                                h0a, h0b, h1a, h1b, c0, c1, fcW, fcb, done);
    }
}

// Round 4
// 9146.243 us; speedup vs baseline: 2.5363x; 1.1747x over previous
//
#include <hip/hip_runtime.h>

typedef short short8 __attribute__((ext_vector_type(8)));
typedef float f32x4 __attribute__((ext_vector_type(4)));

#define SMEM_BYTES (2*64*68*4 + 4*64*4)   // two 64x68 f32 tiles + 4x64 fc-reduce

__device__ __forceinline__ unsigned short f2bf(float x) {
    unsigned int u = __float_as_uint(x);
    u += 0x7FFFu + ((u >> 16) & 1u);   // round-to-nearest-even
    return (unsigned short)(u >> 16);
}

__device__ __forceinline__ float sigmoidf_(float x) {
    return 1.0f / (1.0f + __expf(-x));
}

__device__ __forceinline__ float tanhf_(float x) {
    float ax = fabsf(x);
    float e = __expf(2.0f * ax);
    float t = 1.0f - 2.0f / (e + 1.0f);
    return copysignf(t, x);
}

// ---------------- packed layouts ----------------
// hP  [rg 16][kc 32][lane 64][j 8]  (lane = q*16+m holds h[rg*16+m][kc*32+q*8+j])
// WP  [ug 64][kc K/32][gate 4][lane 64][j 8]
// Every K-loop load is base + lane*16B -> one contiguous 1 KB per instruction.

// One LSTM step tile: 64 batch rows x 16 units (x4 gates).
// 4 waves K-split, 4x4 MFMA register blocking, 4-stage register pipeline
// (needs ~224 VGPRs -> kernels use amdgpu_waves_per_eu(2,2) so the allocator
// doesn't collapse the pipeline).
// Prefetch overruns up to 3 chunks past the slice end -> guard memory required.
//
// Session notes (R1-R3): (a) 512-thread/128-row restructure with shared-tile
// atomicAdd reduction = 2.5x regression — keep 256-thread blocks, two-tile
// non-atomic reduction, 2 blocks/CU overlap. (b) Intra-launch producer/consumer
// fusion of the two decoder layers regressed in every variant: agent-scope
// ACQUIRE polling invalidates the XCD L2 per iteration (R2, ~7x decoder blowup);
// even with relaxed polling the per-block device fences + LLC poller contention
// cost ~+16 us/step vs split launches (R3). Split launches are the optimum here.
template<int K>
__device__ __forceinline__ void lstm_tile(
    int idx,
    const unsigned short* __restrict__ A1,   // hP, first K-half
    const unsigned short* __restrict__ A2,   // hP, second K-half (K==2048) or null
    const unsigned short* __restrict__ W,    // WP packed
    const float* __restrict__ bias,          // [4096]
    const float* __restrict__ xvec, int xstride,
    const float* __restrict__ Wx,            // [4096] or null
    float* __restrict__ c,                   // [256,1024] fp32 in-place
    unsigned short* __restrict__ hout,       // hP packed out
    const float* __restrict__ fcW,
    const float* __restrict__ fcb,
    float* __restrict__ yout)
{
    extern __shared__ float smem[];
    float* T0  = smem;                 // 64 x 68
    float* T1  = smem + 64 * 68;
    float* red = smem + 2 * 64 * 68;   // 4 x 64

    constexpr int KS = K / 4;
    constexpr int NC = KS / 32;        // chunks per wave (8 or 16)
    constexpr int KC = K / 32;
    const int tid  = threadIdx.x;
    const int lane = tid & 63;
    const int wave = tid >> 6;
    const int g  = idx >> 6;           // batch group (64 rows)
    const int ug = idx & 63;           // unit group (16 units)
    const int mb = g * 64;
    const int ub = ug * 16;

    const unsigned short* Af = (K == 1024) ? A1 : (wave < 2 ? A1 : A2);
    const int kcA0 = (wave * NC) & 31;
    const int kcW0 = wave * NC;
    const unsigned short* ap = Af + ((size_t)(g * 4) * 32 + kcA0) * 512 + lane * 8;
    const unsigned short* bp = W + ((size_t)(ug * KC + kcW0) * 4) * 512 + lane * 8;

    f32x4 acc[4][4];
#pragma unroll
    for (int i = 0; i < 4; ++i)
#pragma unroll
        for (int j = 0; j < 4; ++j) acc[i][j] = (f32x4){0.f, 0.f, 0.f, 0.f};

    short8 aS[4][4], bS[4][4];
    auto LD = [&](int s, int cc) {
#pragma unroll
        for (int mi = 0; mi < 4; ++mi)
            aS[s][mi] = *(const short8*)(ap + mi * 16384 + cc * 512);
#pragma unroll
        for (int gt = 0; gt < 4; ++gt)
            bS[s][gt] = *(const short8*)(bp + (cc * 4 + gt) * 512);
    };
    auto MM = [&](int s) {
#pragma unroll
        for (int mi = 0; mi < 4; ++mi)
#pragma unroll
            for (int gt = 0; gt < 4; ++gt)
                acc[mi][gt] = __builtin_amdgcn_mfma_f32_16x16x32_bf16(
                    aS[s][mi], bS[s][gt], acc[mi][gt], 0, 0, 0);
    };

    LD(0, 0); LD(1, 1); LD(2, 2); LD(3, 3);
#pragma unroll
    for (int cc = 0; cc < NC; cc += 4) {
        MM(0); LD(0, cc + 4);    // tail iters overrun into guard memory
        MM(1); LD(1, cc + 5);
        MM(2); LD(2, cc + 6);
        MM(3); LD(3, cc + 7);
    }

    // ---- K-split reduction through LDS ----
    const int q = lane >> 4;
    const int m = lane & 15;
    float* Tw = (wave & 1) ? T1 : T0;
    if (wave < 2) {
#pragma unroll
        for (int mi = 0; mi < 4; ++mi)
#pragma unroll
            for (int gt = 0; gt < 4; ++gt)
#pragma unroll
                for (int r = 0; r < 4; ++r)
                    Tw[(mi * 16 + q * 4 + r) * 68 + gt * 16 + m] = acc[mi][gt][r];
    }
    __syncthreads();
    if (wave >= 2) {
#pragma unroll
        for (int mi = 0; mi < 4; ++mi)
#pragma unroll
            for (int gt = 0; gt < 4; ++gt)
#pragma unroll
                for (int r = 0; r < 4; ++r)
                    Tw[(mi * 16 + q * 4 + r) * 68 + gt * 16 + m] += acc[mi][gt][r];
    }
    __syncthreads();

    // ---- epilogue: thread owns (row = tid>>2, units u0..u0+3) ----
    const int lrow = tid >> 2;
    const int uq   = tid & 3;
    const int br   = mb + lrow;
    const int u0   = ub + uq * 4;
    const int toff = lrow * 68 + uq * 4;

    auto gate4 = [&](int gofs) -> float4 {
        float4 a = *(const float4*)(T0 + toff + gofs);
        float4 b = *(const float4*)(T1 + toff + gofs);
        return make_float4(a.x + b.x, a.y + b.y, a.z + b.z, a.w + b.w);
    };
    float4 GI = gate4(0), GF = gate4(16), GG = gate4(32), GO = gate4(48);
    float4 bI = *(const float4*)(bias + u0);
    float4 bF = *(const float4*)(bias + 1024 + u0);
    float4 bG = *(const float4*)(bias + 2048 + u0);
    float4 bO = *(const float4*)(bias + 3072 + u0);
    float4 wI = {0,0,0,0}, wF = {0,0,0,0}, wG = {0,0,0,0}, wO = {0,0,0,0};
    float xv = 0.f;
    if (xvec) {
        xv = xvec[br * xstride];
        wI = *(const float4*)(Wx + u0);
        wF = *(const float4*)(Wx + 1024 + u0);
        wG = *(const float4*)(Wx + 2048 + u0);
        wO = *(const float4*)(Wx + 3072 + u0);
    }
    float4 cc = *(const float4*)(c + (size_t)br * 1024 + u0);

    auto cellc = [&](float gi, float gf, float gg, float go, float cold, float& hO) -> float {
        float i = sigmoidf_(gi);
        float f = sigmoidf_(gf);
        float o = sigmoidf_(go);
        float cn = f * cold + i * tanhf_(gg);
        hO = o * tanhf_(cn);
        return cn;
    };
    float h0v, h1v, h2v, h3v;
    float4 cn;
    cn.x = cellc(GI.x + bI.x + xv * wI.x, GF.x + bF.x + xv * wF.x,
                 GG.x + bG.x + xv * wG.x, GO.x + bO.x + xv * wO.x, cc.x, h0v);
    cn.y = cellc(GI.y + bI.y + xv * wI.y, GF.y + bF.y + xv * wF.y,
                 GG.y + bG.y + xv * wG.y, GO.y + bO.y + xv * wO.y, cc.y, h1v);
    cn.z = cellc(GI.z + bI.z + xv * wI.z, GF.z + bF.z + xv * wF.z,
                 GG.z + bG.z + xv * wG.z, GO.z + bO.z + xv * wO.z, cc.z, h2v);
    cn.w = cellc(GI.w + bI.w + xv * wI.w, GF.w + bF.w + xv * wF.w,
                 GG.w + bG.w + xv * wG.w, GO.w + bO.w + xv * wO.w, cc.w, h3v);
    *(float4*)(c + (size_t)br * 1024 + u0) = cn;

    // packed h store: hP[rg][kc][q*16+m][j]
    {
        const int rg = br >> 4, ml = br & 15;
        const int kc = u0 >> 5, qq = (u0 >> 3) & 3, jo = u0 & 7;
        ushort4 hu;
        hu.x = f2bf(h0v); hu.y = f2bf(h1v); hu.z = f2bf(h2v); hu.w = f2bf(h3v);
        *(ushort4*)(hout + ((size_t)(rg * 32 + kc) * 64 + qq * 16 + ml) * 8 + jo) = hu;
    }

    if (fcW) {
        float4 fw = *(const float4*)(fcW + u0);
        float fcp = h0v * fw.x + h1v * fw.y + h2v * fw.z + h3v * fw.w;
        red[uq * 64 + lrow] = fcp;
        __syncthreads();
        if (tid < 64) {
            float s = red[tid] + red[64 + tid] + red[128 + tid] + red[192 + tid];
            if (ub == 0) s += fcb[0];
            atomicAdd(yout + (size_t)(mb + tid) * 96, s);
        }
    }
}

// Encoder: blocks 0..255 layer0 step t; 256..511 layer1 step t-1 (pipelined).
__global__ __launch_bounds__(256)
__attribute__((amdgpu_waves_per_eu(2, 2)))
void k_enc_step(
    int t,
    const float* __restrict__ x,
    const float* __restrict__ Wih0, const float* __restrict__ b0,
    const unsigned short* __restrict__ Wenc0,
    const unsigned short* __restrict__ Wenc1, const float* __restrict__ b1,
    unsigned short* h0a, unsigned short* h0b,
    unsigned short* h1a, unsigned short* h1b,
    float* c0, float* c1)
{
    unsigned short* h0[2] = {h0a, h0b};
    unsigned short* h1[2] = {h1a, h1b};
    const int blk = blockIdx.x;
    if (blk < 256) {
        if (t >= 336) return;
        lstm_tile<1024>(blk, h0[(t + 1) & 1], nullptr, Wenc0, b0,
                        x + t, 336, Wih0, c0, h0[t & 1],
                        nullptr, nullptr, nullptr);
    } else {
        const int u = t - 1;
        if (u < 0) return;
        lstm_tile<2048>(blk - 256, h0[u & 1], h1[(u + 1) & 1], Wenc1, b1,
                        nullptr, 0, nullptr, c1, h1[u & 1],
                        nullptr, nullptr, nullptr);
    }
}

__global__ __launch_bounds__(256)
__attribute__((amdgpu_waves_per_eu(2, 2)))
void k_dec0(
    int s,
    const float* __restrict__ x,
    const float* __restrict__ dout,
    const float* __restrict__ Wih0, const float* __restrict__ b0,
    const unsigned short* __restrict__ Wdec0,
    unsigned short* h0a, unsigned short* h0b, float* c0)
{
    unsigned short* h0[2] = {h0a, h0b};
    const float* xv; int xs;
    if (s == 0) { xv = x + 335; xs = 336; }
    else        { xv = dout + (s - 1); xs = 96; }
    lstm_tile<1024>(blockIdx.x, h0[(s + 1) & 1], nullptr, Wdec0, b0,
                    xv, xs, Wih0, c0, h0[s & 1],
                    nullptr, nullptr, nullptr);
}

__global__ __launch_bounds__(256)
__attribute__((amdgpu_waves_per_eu(2, 2)))
void k_dec1(
    int s,
    const unsigned short* __restrict__ Wdec1, const float* __restrict__ b1,
    unsigned short* h0a, unsigned short* h0b,
    unsigned short* h1a, unsigned short* h1b,
    float* c1,
    const float* __restrict__ fcW, const float* __restrict__ fcb,
    float* __restrict__ dout)
{
    unsigned short* h0[2] = {h0a, h0b};
    unsigned short* h1[2] = {h1a, h1b};
    lstm_tile<2048>(blockIdx.x, h0[s & 1], h1[(s + 1) & 1], Wdec1, b1,
                    nullptr, 0, nullptr, c1, h1[s & 1],
                    fcW, fcb, dout + s);
}

// ---- prep: pack fp32 weights into WP fragment order (bf16) ----
template<int K>
__global__ void k_packW(const float* __restrict__ srcA, const float* __restrict__ srcB,
                        unsigned short* __restrict__ dst)
{
    constexpr int KC = K / 32;
    const int total = 4096 * K / 8;
    const int du = blockIdx.x * blockDim.x + threadIdx.x;
    if (du >= total) return;
    const int lane = du & 63;
    int rest = du >> 6;
    const int gate = rest & 3; rest >>= 2;
    const int kc = rest % KC;
    const int ug = rest / KC;
    const int q = lane >> 4, m = lane & 15;
    const int row = gate * 1024 + ug * 16 + m;
    const int k = kc * 32 + q * 8;
    const float* s;
    if (K == 2048 && k >= 1024) s = srcB + (size_t)row * 1024 + (k - 1024);
    else                        s = srcA + (size_t)row * 1024 + k;
    const float4 v0 = *(const float4*)(s);
    const float4 v1 = *(const float4*)(s + 4);
    short8 o;
    o[0] = (short)f2bf(v0.x); o[1] = (short)f2bf(v0.y);
    o[2] = (short)f2bf(v0.z); o[3] = (short)f2bf(v0.w);
    o[4] = (short)f2bf(v1.x); o[5] = (short)f2bf(v1.y);
    o[6] = (short)f2bf(v1.z); o[7] = (short)f2bf(v1.w);
    *(short8*)(dst + (size_t)du * 8) = o;
}

extern "C" void kernel_launch(void* const* d_in, const int* in_sizes, int n_in,
                              void* d_out, int out_size, void* d_ws, size_t ws_size,
                              hipStream_t stream)
{
    const float* x     = (const float*)d_in[0];
    const float* eWih0 = (const float*)d_in[1];
    const float* eWhh0 = (const float*)d_in[2];
    const float* eb0   = (const float*)d_in[3];
    const float* eWih1 = (const float*)d_in[4];
    const float* eWhh1 = (const float*)d_in[5];
    const float* eb1   = (const float*)d_in[6];
    const float* dWih0 = (const float*)d_in[7];
    const float* dWhh0 = (const float*)d_in[8];
    const float* db0   = (const float*)d_in[9];
    const float* dWih1 = (const float*)d_in[10];
    const float* dWhh1 = (const float*)d_in[11];
    const float* db1   = (const float*)d_in[12];
    const float* fcW   = (const float*)d_in[13];
    const float* fcb   = (const float*)d_in[14];
    float* out = (float*)d_out;

    char* ws = (char*)d_ws;
    size_t off = 0;
    auto walloc = [&](size_t bytes) -> void* {
        void* p = ws + off;
        off = (off + bytes + 255) & ~(size_t)255;
        return p;
    };
    unsigned short* Wenc0 = (unsigned short*)walloc((size_t)4096 * 1024 * 2 + 32768);
    unsigned short* Wenc1 = (unsigned short*)walloc((size_t)4096 * 2048 * 2 + 32768);
    unsigned short* Wdec0 = (unsigned short*)walloc((size_t)4096 * 1024 * 2 + 32768);
    unsigned short* Wdec1 = (unsigned short*)walloc((size_t)4096 * 2048 * 2 + 32768);
    const size_t STATE = (size_t)4 * 524288 + (size_t)2 * 1048576;
    char* stateBase = (char*)walloc(STATE + 65536);   // + guard for prefetch overrun
    unsigned short* h0a = (unsigned short*)(stateBase);
    unsigned short* h0b = (unsigned short*)(stateBase + 524288);
    unsigned short* h1a = (unsigned short*)(stateBase + 2 * 524288);
    unsigned short* h1b = (unsigned short*)(stateBase + 3 * 524288);
    float* c0 = (float*)(stateBase + 4 * 524288);
    float* c1 = (float*)(stateBase + 4 * 524288 + 1048576);

    hipMemsetAsync(stateBase, 0, STATE, stream);
    hipMemsetAsync(d_out, 0, (size_t)out_size * sizeof(float), stream);

    {
        const int n1 = 4096 * 1024 / 8;
        const int n2 = 4096 * 2048 / 8;
        k_packW<1024><<<n1 / 256, 256, 0, stream>>>(eWhh0, nullptr, Wenc0);
        k_packW<1024><<<n1 / 256, 256, 0, stream>>>(dWhh0, nullptr, Wdec0);
        k_packW<2048><<<n2 / 256, 256, 0, stream>>>(eWih1, eWhh1, Wenc1);
        k_packW<2048><<<n2 / 256, 256, 0, stream>>>(dWih1, dWhh1, Wdec1);
    }

    for (int t = 0; t <= 336; ++t) {
        k_enc_step<<<512, 256, SMEM_BYTES, stream>>>(t, x, eWih0, eb0, Wenc0, Wenc1, eb1,
                                                     h0a, h0b, h1a, h1b, c0, c1);
    }
    for (int s = 0; s < 96; ++s) {
        k_dec0<<<256, 256, SMEM_BYTES, stream>>>(s, x, out, dWih0, db0, Wdec0, h0a, h0b, c0);
        k_dec1<<<256, 256, SMEM_BYTES, stream>>>(s, Wdec1, db1, h0a, h0b, h1a, h1b, c1,
                                                 fcW, fcb, out);
    }
}

// Round 5
// 6660.410 us; speedup vs baseline: 3.4829x; 1.3732x over previous
//
#include <hip/hip_runtime.h>

typedef short short8 __attribute__((ext_vector_type(8)));
typedef float f32x4 __attribute__((ext_vector_type(4)));

// LDS: [0,65536) = union { loop: stage[4 waves][2 bufs][8192B],
//                          epilogue: T0(64x68 f32)=17408B, T1=17408B }
//      [65536,66560) = red (4x64 f32)
#define SMEM_BYTES (65536 + 1024)

__device__ __forceinline__ unsigned short f2bf(float x) {
    unsigned int u = __float_as_uint(x);
    u += 0x7FFFu + ((u >> 16) & 1u);   // round-to-nearest-even
    return (unsigned short)(u >> 16);
}

__device__ __forceinline__ float sigmoidf_(float x) {
    return 1.0f / (1.0f + __expf(-x));
}

__device__ __forceinline__ float tanhf_(float x) {
    float ax = fabsf(x);
    float e = __expf(2.0f * ax);
    float t = 1.0f - 2.0f / (e + 1.0f);
    return copysignf(t, x);
}

// async global->LDS, 16B per lane. Global src is PER-LANE, LDS dst must be
// WAVE-UNIFORM (HW adds lane*16).
__device__ __forceinline__ void gl_lds16(const void* g, void* l) {
    __builtin_amdgcn_global_load_lds(
        (const __attribute__((address_space(1))) void*)g,
        (__attribute__((address_space(3))) void*)l, 16, 0, 0);
}

// ---------------- packed layouts ----------------
// hP  [rg 16][kc 32][lane 64][j 8]  (lane = q*16+m holds h[rg*16+m][kc*32+q*8+j])
// WP  [ug 64][kc K/32][gate 4][lane 64][j 8]
// Every staged chunk piece is one contiguous 1 KB per wave-instruction.

// One LSTM step tile: 64 batch rows x 16 units (x4 gates).
// 4 waves K-split. K-loop uses per-wave double-buffered LDS DMA staging
// (global_load_lds w=16): fire-and-forget loads, counted s_waitcnt vmcnt(8),
// NO intra-loop barriers (each wave owns its 2x8KB buffers). Per-CU ingest is
// the binding resource (~34-50 GB/s/CU measured via R0/R4 timing fits); DMA
// staging raises streaming MLP vs register staging (guide m151: +35%).
// Staging LDS aliases the T0/T1 reduction tiles: loop phase and epilogue
// phase are separated by vmcnt(0) + __syncthreads.
// Prefetch overruns 1 chunk past the slice end -> guard memory required.
//
// Session notes (R1-R3): (a) 512-thread/128-row restructure with shared-tile
// atomicAdd reduction = 2.5x regression — keep 256-thread blocks, two-tile
// non-atomic reduction, 2 blocks/CU overlap. (b) Intra-launch producer/consumer
// fusion of the two decoder layers regressed in every variant: agent-scope
// ACQUIRE polling invalidates the XCD L2 per iteration (R2, ~7x decoder blowup);
// even with relaxed polling the per-block device fences + LLC poller contention
// cost ~+16 us/step vs split launches (R3). Split launches are the optimum here.
template<int K>
__device__ __forceinline__ void lstm_tile(
    int idx,
    const unsigned short* __restrict__ A1,   // hP, first K-half
    const unsigned short* __restrict__ A2,   // hP, second K-half (K==2048) or null
    const unsigned short* __restrict__ W,    // WP packed
    const float* __restrict__ bias,          // [4096]
    const float* __restrict__ xvec, int xstride,
    const float* __restrict__ Wx,            // [4096] or null
    float* __restrict__ c,                   // [256,1024] fp32 in-place
    unsigned short* __restrict__ hout,       // hP packed out
    const float* __restrict__ fcW,
    const float* __restrict__ fcb,
    float* __restrict__ yout)
{
    extern __shared__ char smem_raw[];
    float* T0  = (float*)smem_raw;                 // 64 x 68 (aliases staging)
    float* T1  = (float*)(smem_raw + 17408);
    float* red = (float*)(smem_raw + 65536);       // 4 x 64

    constexpr int KS = K / 4;
    constexpr int NC = KS / 32;        // chunks per wave (8 or 16)
    constexpr int KC = K / 32;
    const int tid  = threadIdx.x;
    const int lane = tid & 63;
    const int wave = tid >> 6;
    const int g  = idx >> 6;           // batch group (64 rows)
    const int ug = idx & 63;           // unit group (16 units)
    const int mb = g * 64;
    const int ub = ug * 16;

    const unsigned short* Af = (K == 1024) ? A1 : (wave < 2 ? A1 : A2);
    const int kcA0 = (wave * NC) & 31;
    const int kcW0 = wave * NC;
    const unsigned short* ap = Af + ((size_t)(g * 4) * 32 + kcA0) * 512 + lane * 8;
    const unsigned short* bp = W + ((size_t)(ug * KC + kcW0) * 4) * 512 + lane * 8;

    char* stg = smem_raw + wave * 16384;   // 2 x 8KB per wave

    f32x4 acc[4][4];
#pragma unroll
    for (int i = 0; i < 4; ++i)
#pragma unroll
        for (int j = 0; j < 4; ++j) acc[i][j] = (f32x4){0.f, 0.f, 0.f, 0.f};

    // stage chunk cc into buffer buf: pieces 0..3 = A(mi), 4..7 = B(gt)
    auto STAGE = [&](int cc, int buf) {
        char* dst = stg + buf * 8192;
        const unsigned short* asrc = ap + cc * 512;
        const unsigned short* bsrc = bp + cc * 2048;
#pragma unroll
        for (int mi = 0; mi < 4; ++mi)
            gl_lds16(asrc + mi * 16384, dst + mi * 1024);
#pragma unroll
        for (int gt = 0; gt < 4; ++gt)
            gl_lds16(bsrc + gt * 512, dst + 4096 + gt * 1024);
    };
    auto CONSUME = [&](int buf) {
        const char* src = stg + buf * 8192;
        short8 a[4], b[4];
#pragma unroll
        for (int p = 0; p < 4; ++p)
            a[p] = *(const short8*)(src + p * 1024 + lane * 16);
#pragma unroll
        for (int p = 0; p < 4; ++p)
            b[p] = *(const short8*)(src + 4096 + p * 1024 + lane * 16);
#pragma unroll
        for (int mi = 0; mi < 4; ++mi)
#pragma unroll
            for (int gt = 0; gt < 4; ++gt)
                acc[mi][gt] = __builtin_amdgcn_mfma_f32_16x16x32_bf16(
                    a[mi], b[gt], acc[mi][gt], 0, 0, 0);
    };

    STAGE(0, 0);
#pragma unroll
    for (int cc = 0; cc < NC; ++cc) {
        STAGE(cc + 1, (cc + 1) & 1);   // cc+1==NC overruns into guard memory
        // wait until only the 8 just-issued DMAs are outstanding -> chunk cc landed
        asm volatile("s_waitcnt vmcnt(8)" ::: "memory");
        __builtin_amdgcn_sched_barrier(0);
        CONSUME(cc & 1);
    }
    asm volatile("s_waitcnt vmcnt(0)" ::: "memory");  // drain tail DMA before LDS reuse
    __syncthreads();

    // ---- K-split reduction through LDS (staging region now reused as T0/T1) ----
    const int q = lane >> 4;
    const int m = lane & 15;
    float* Tw = (wave & 1) ? T1 : T0;
    if (wave < 2) {
#pragma unroll
        for (int mi = 0; mi < 4; ++mi)
#pragma unroll
            for (int gt = 0; gt < 4; ++gt)
#pragma unroll
                for (int r = 0; r < 4; ++r)
                    Tw[(mi * 16 + q * 4 + r) * 68 + gt * 16 + m] = acc[mi][gt][r];
    }
    __syncthreads();
    if (wave >= 2) {
#pragma unroll
        for (int mi = 0; mi < 4; ++mi)
#pragma unroll
            for (int gt = 0; gt < 4; ++gt)
#pragma unroll
                for (int r = 0; r < 4; ++r)
                    Tw[(mi * 16 + q * 4 + r) * 68 + gt * 16 + m] += acc[mi][gt][r];
    }
    __syncthreads();

    // ---- epilogue: thread owns (row = tid>>2, units u0..u0+3) ----
    const int lrow = tid >> 2;
    const int uq   = tid & 3;
    const int br   = mb + lrow;
    const int u0   = ub + uq * 4;
    const int toff = lrow * 68 + uq * 4;

    auto gate4 = [&](int gofs) -> float4 {
        float4 a = *(const float4*)(T0 + toff + gofs);
        float4 b = *(const float4*)(T1 + toff + gofs);
        return make_float4(a.x + b.x, a.y + b.y, a.z + b.z, a.w + b.w);
    };
    float4 GI = gate4(0), GF = gate4(16), GG = gate4(32), GO = gate4(48);
    float4 bI = *(const float4*)(bias + u0);
    float4 bF = *(const float4*)(bias + 1024 + u0);
    float4 bG = *(const float4*)(bias + 2048 + u0);
    float4 bO = *(const float4*)(bias + 3072 + u0);
    float4 wI = {0,0,0,0}, wF = {0,0,0,0}, wG = {0,0,0,0}, wO = {0,0,0,0};
    float xv = 0.f;
    if (xvec) {
        xv = xvec[br * xstride];
        wI = *(const float4*)(Wx + u0);
        wF = *(const float4*)(Wx + 1024 + u0);
        wG = *(const float4*)(Wx + 2048 + u0);
        wO = *(const float4*)(Wx + 3072 + u0);
    }
    float4 cc = *(const float4*)(c + (size_t)br * 1024 + u0);

    auto cellc = [&](float gi, float gf, float gg, float go, float cold, float& hO) -> float {
        float i = sigmoidf_(gi);
        float f = sigmoidf_(gf);
        float o = sigmoidf_(go);
        float cn = f * cold + i * tanhf_(gg);
        hO = o * tanhf_(cn);
        return cn;
    };
    float h0v, h1v, h2v, h3v;
    float4 cn;
    cn.x = cellc(GI.x + bI.x + xv * wI.x, GF.x + bF.x + xv * wF.x,
                 GG.x + bG.x + xv * wG.x, GO.x + bO.x + xv * wO.x, cc.x, h0v);
    cn.y = cellc(GI.y + bI.y + xv * wI.y, GF.y + bF.y + xv * wF.y,
                 GG.y + bG.y + xv * wG.y, GO.y + bO.y + xv * wO.y, cc.y, h1v);
    cn.z = cellc(GI.z + bI.z + xv * wI.z, GF.z + bF.z + xv * wF.z,
                 GG.z + bG.z + xv * wG.z, GO.z + bO.z + xv * wO.z, cc.z, h2v);
    cn.w = cellc(GI.w + bI.w + xv * wI.w, GF.w + bF.w + xv * wF.w,
                 GG.w + bG.w + xv * wG.w, GO.w + bO.w + xv * wO.w, cc.w, h3v);
    *(float4*)(c + (size_t)br * 1024 + u0) = cn;

    // packed h store: hP[rg][kc][q*16+m][j]
    {
        const int rg = br >> 4, ml = br & 15;
        const int kc = u0 >> 5, qq = (u0 >> 3) & 3, jo = u0 & 7;
        ushort4 hu;
        hu.x = f2bf(h0v); hu.y = f2bf(h1v); hu.z = f2bf(h2v); hu.w = f2bf(h3v);
        *(ushort4*)(hout + ((size_t)(rg * 32 + kc) * 64 + qq * 16 + ml) * 8 + jo) = hu;
    }

    if (fcW) {
        float4 fw = *(const float4*)(fcW + u0);
        float fcp = h0v * fw.x + h1v * fw.y + h2v * fw.z + h3v * fw.w;
        red[uq * 64 + lrow] = fcp;
        __syncthreads();
        if (tid < 64) {
            float s = red[tid] + red[64 + tid] + red[128 + tid] + red[192 + tid];
            if (ub == 0) s += fcb[0];
            atomicAdd(yout + (size_t)(mb + tid) * 96, s);
        }
    }
}

// Encoder: blocks 0..255 layer0 step t; 256..511 layer1 step t-1 (pipelined).
__global__ __launch_bounds__(256)
__attribute__((amdgpu_waves_per_eu(2, 2)))
void k_enc_step(
    int t,
    const float* __restrict__ x,
    const float* __restrict__ Wih0, const float* __restrict__ b0,
    const unsigned short* __restrict__ Wenc0,
    const unsigned short* __restrict__ Wenc1, const float* __restrict__ b1,
    unsigned short* h0a, unsigned short* h0b,
    unsigned short* h1a, unsigned short* h1b,
    float* c0, float* c1)
{
    unsigned short* h0[2] = {h0a, h0b};
    unsigned short* h1[2] = {h1a, h1b};
    const int blk = blockIdx.x;
    if (blk < 256) {
        if (t >= 336) return;
        lstm_tile<1024>(blk, h0[(t + 1) & 1], nullptr, Wenc0, b0,
                        x + t, 336, Wih0, c0, h0[t & 1],
                        nullptr, nullptr, nullptr);
    } else {
        const int u = t - 1;
        if (u < 0) return;
        lstm_tile<2048>(blk - 256, h0[u & 1], h1[(u + 1) & 1], Wenc1, b1,
                        nullptr, 0, nullptr, c1, h1[u & 1],
                        nullptr, nullptr, nullptr);
    }
}

__global__ __launch_bounds__(256)
__attribute__((amdgpu_waves_per_eu(2, 2)))
void k_dec0(
    int s,
    const float* __restrict__ x,
    const float* __restrict__ dout,
    const float* __restrict__ Wih0, const float* __restrict__ b0,
    const unsigned short* __restrict__ Wdec0,
    unsigned short* h0a, unsigned short* h0b, float* c0)
{
    unsigned short* h0[2] = {h0a, h0b};
    const float* xv; int xs;
    if (s == 0) { xv = x + 335; xs = 336; }
    else        { xv = dout + (s - 1); xs = 96; }
    lstm_tile<1024>(blockIdx.x, h0[(s + 1) & 1], nullptr, Wdec0, b0,
                    xv, xs, Wih0, c0, h0[s & 1],
                    nullptr, nullptr, nullptr);
}

__global__ __launch_bounds__(256)
__attribute__((amdgpu_waves_per_eu(2, 2)))
void k_dec1(
    int s,
    const unsigned short* __restrict__ Wdec1, const float* __restrict__ b1,
    unsigned short* h0a, unsigned short* h0b,
    unsigned short* h1a, unsigned short* h1b,
    float* c1,
    const float* __restrict__ fcW, const float* __restrict__ fcb,
    float* __restrict__ dout)
{
    unsigned short* h0[2] = {h0a, h0b};
    unsigned short* h1[2] = {h1a, h1b};
    lstm_tile<2048>(blockIdx.x, h0[s & 1], h1[(s + 1) & 1], Wdec1, b1,
                    nullptr, 0, nullptr, c1, h1[s & 1],
                    fcW, fcb, dout + s);
}

// ---- prep: pack fp32 weights into WP fragment order (bf16) ----
template<int K>
__global__ void k_packW(const float* __restrict__ srcA, const float* __restrict__ srcB,
                        unsigned short* __restrict__ dst)
{
    constexpr int KC = K / 32;
    const int total = 4096 * K / 8;
    const int du = blockIdx.x * blockDim.x + threadIdx.x;
    if (du >= total) return;
    const int lane = du & 63;
    int rest = du >> 6;
    const int gate = rest & 3; rest >>= 2;
    const int kc = rest % KC;
    const int ug = rest / KC;
    const int q = lane >> 4, m = lane & 15;
    const int row = gate * 1024 + ug * 16 + m;
    const int k = kc * 32 + q * 8;
    const float* s;
    if (K == 2048 && k >= 1024) s = srcB + (size_t)row * 1024 + (k - 1024);
    else                        s = srcA + (size_t)row * 1024 + k;
    const float4 v0 = *(const float4*)(s);
    const float4 v1 = *(const float4*)(s + 4);
    short8 o;
    o[0] = (short)f2bf(v0.x); o[1] = (short)f2bf(v0.y);
    o[2] = (short)f2bf(v0.z); o[3] = (short)f2bf(v0.w);
    o[4] = (short)f2bf(v1.x); o[5] = (short)f2bf(v1.y);
    o[6] = (short)f2bf(v1.z); o[7] = (short)f2bf(v1.w);
    *(short8*)(dst + (size_t)du * 8) = o;
}

extern "C" void kernel_launch(void* const* d_in, const int* in_sizes, int n_in,
                              void* d_out, int out_size, void* d_ws, size_t ws_size,
                              hipStream_t stream)
{
    const float* x     = (const float*)d_in[0];
    const float* eWih0 = (const float*)d_in[1];
    const float* eWhh0 = (const float*)d_in[2];
    const float* eb0   = (const float*)d_in[3];
    const float* eWih1 = (const float*)d_in[4];
    const float* eWhh1 = (const float*)d_in[5];
    const float* eb1   = (const float*)d_in[6];
    const float* dWih0 = (const float*)d_in[7];
    const float* dWhh0 = (const float*)d_in[8];
    const float* db0   = (const float*)d_in[9];
    const float* dWih1 = (const float*)d_in[10];
    const float* dWhh1 = (const float*)d_in[11];
    const float* db1   = (const float*)d_in[12];
    const float* fcW   = (const float*)d_in[13];
    const float* fcb   = (const float*)d_in[14];
    float* out = (float*)d_out;

    char* ws = (char*)d_ws;
    size_t off = 0;
    auto walloc = [&](size_t bytes) -> void* {
        void* p = ws + off;
        off = (off + bytes + 255) & ~(size_t)255;
        return p;
    };
    unsigned short* Wenc0 = (unsigned short*)walloc((size_t)4096 * 1024 * 2 + 32768);
    unsigned short* Wenc1 = (unsigned short*)walloc((size_t)4096 * 2048 * 2 + 32768);
    unsigned short* Wdec0 = (unsigned short*)walloc((size_t)4096 * 1024 * 2 + 32768);
    unsigned short* Wdec1 = (unsigned short*)walloc((size_t)4096 * 2048 * 2 + 32768);
    const size_t STATE = (size_t)4 * 524288 + (size_t)2 * 1048576;
    char* stateBase = (char*)walloc(STATE + 65536);   // + guard for prefetch overrun
    unsigned short* h0a = (unsigned short*)(stateBase);
    unsigned short* h0b = (unsigned short*)(stateBase + 524288);
    unsigned short* h1a = (unsigned short*)(stateBase + 2 * 524288);
    unsigned short* h1b = (unsigned short*)(stateBase + 3 * 524288);
    float* c0 = (float*)(stateBase + 4 * 524288);
    float* c1 = (float*)(stateBase + 4 * 524288 + 1048576);

    hipMemsetAsync(stateBase, 0, STATE, stream);
    hipMemsetAsync(d_out, 0, (size_t)out_size * sizeof(float), stream);

    {
        const int n1 = 4096 * 1024 / 8;
        const int n2 = 4096 * 2048 / 8;
        k_packW<1024><<<n1 / 256, 256, 0, stream>>>(eWhh0, nullptr, Wenc0);
        k_packW<1024><<<n1 / 256, 256, 0, stream>>>(dWhh0, nullptr, Wdec0);
        k_packW<2048><<<n2 / 256, 256, 0, stream>>>(eWih1, eWhh1, Wenc1);
        k_packW<2048><<<n2 / 256, 256, 0, stream>>>(dWih1, dWhh1, Wdec1);
    }

    for (int t = 0; t <= 336; ++t) {
        k_enc_step<<<512, 256, SMEM_BYTES, stream>>>(t, x, eWih0, eb0, Wenc0, Wenc1, eb1,
                                                     h0a, h0b, h1a, h1b, c0, c1);
    }
    for (int s = 0; s < 96; ++s) {
        k_dec0<<<256, 256, SMEM_BYTES, stream>>>(s, x, out, dWih0, db0, Wdec0, h0a, h0b, c0);
        k_dec1<<<256, 256, SMEM_BYTES, stream>>>(s, Wdec1, db1, h0a, h0b, h1a, h1b, c1,
                                                 fcW, fcb, out);
    }
}